// Round 7
// baseline (507.999 us; speedup 1.0000x reference)
//
#include <hip/hip_runtime.h>
#include <hip/hip_cooperative_groups.h>

namespace cg = cooperative_groups;

#define BATCH   32
#define DIM     128
#define NBASES  8
#define SSTEPS  128
#define MAT     (DIM*DIM)
#define NELEM   (BATCH*MAT)

// ---- scratch in device globals (.bss, ~18.5 MB); every buffer fully written
// before read within each call ----
__device__ __align__(16) float g_rs[NELEM];
__device__ __align__(16) float g_ks[NELEM];
__device__ __align__(16) float g_X [NELEM];
__device__ __align__(16) float g_X2[NELEM];
__device__ __align__(16) float g_c0[NELEM];   // M^T
__device__ __align__(16) float g_c1[NELEM];   // (M^2)^T
__device__ __align__(16) float g_c2[NELEM];   // (M^4)^T
__device__ __align__(16) float g_c3[NELEM];   // (M^8)^T
__device__ __align__(16) float g_c4[NELEM];   // (M^16)^T
__device__ __align__(16) float g_U [BATCH * 2 * 16 * DIM];   // seeds u_1..u_16

// ================= 16-row panel matmul, 256 threads =================
// Block: 16 rows x 128 cols of one batch matrix. Thread t: rows rbase..rbase+3
// (tr = t>>6 wave-uniform -> A loads broadcast), cols 2tc, 2tc+1 (float2 B).
// POLYA: A(r,k) = fa0*I + fa1*X + fa2*X2 (on the fly)
// EPI:   O += ea0*I + ea1*X
// TRANS: transposed store (O[c,r]) -> chain holds M^T
template<bool POLYA, bool EPI, bool TRANS>
__device__ __forceinline__ void mm_panel(
    const float* __restrict__ A, const float* __restrict__ Bm, float* __restrict__ O,
    const float* __restrict__ Xb, const float* __restrict__ X2b,
    float fa0, float fa1, float fa2, float ea0, float ea1,
    int r0, int t)
{
    const int tr = t >> 6, tc = t & 63;
    const int rbase = r0 + tr * 4;
    float ax[4] = {0.f, 0.f, 0.f, 0.f};
    float ay[4] = {0.f, 0.f, 0.f, 0.f};
    for (int k = 0; k < DIM; ++k) {
        const float2 bv = *reinterpret_cast<const float2*>(Bm + k * DIM + tc * 2);
        #pragma unroll
        for (int i = 0; i < 4; ++i) {
            const int r = rbase + i;
            float a;
            if (POLYA) {
                a = fa1 * Xb[r * DIM + k] + fa2 * X2b[r * DIM + k];
                if (k == r) a += fa0;
            } else {
                a = A[r * DIM + k];
            }
            ax[i] += a * bv.x;
            ay[i] += a * bv.y;
        }
    }
    #pragma unroll
    for (int i = 0; i < 4; ++i) {
        const int r = rbase + i;
        const int jx = tc * 2, jy = jx + 1;
        float vx = ax[i], vy = ay[i];
        if (EPI) {
            vx += ea1 * Xb[r * DIM + jx]; if (r == jx) vx += ea0;
            vy += ea1 * Xb[r * DIM + jy]; if (r == jy) vy += ea0;
        }
        if (TRANS) { O[jx * DIM + r] = vx; O[jy * DIM + r] = vy; }
        else       { O[r * DIM + jx] = vx; O[r * DIM + jy] = vy; }
    }
}

__device__ __forceinline__ void write_out(float* __restrict__ outF, int b, int sidx,
                                          int o, int c, float val,
                                          int interleaved, int out_size)
{
    if (interleaved) {
        const int oi = ((b * SSTEPS + sidx) * DIM + o) * 2 + c;
        if (oi < out_size) outF[oi] = val;
    } else if (c == 0) {
        const int oi = (b * SSTEPS + sidx) * DIM + o;
        if (oi < out_size) outF[oi] = val;
    }
}

// one 128x128 mat-vec pair (both complex comps) from LDS vector; W row-major-T
// W[i*DIM+o] = M[o,i]; thread (c = t>>7, o = t&127) -> u_new[o] = sum_i M[o,i]u[i]
__device__ __forceinline__ float matvec_T(const float* __restrict__ W,
                                          const float* __restrict__ v, int c, int o)
{
    float a0 = 0.f, a1 = 0.f, a2 = 0.f, a3 = 0.f;
    const float* vb = v + c * DIM;
    for (int i = 0; i < DIM; i += 4) {
        a0 += W[(i + 0) * DIM + o] * vb[i + 0];
        a1 += W[(i + 1) * DIM + o] * vb[i + 1];
        a2 += W[(i + 2) * DIM + o] * vb[i + 2];
        a3 += W[(i + 3) * DIM + o] * vb[i + 3];
    }
    return (a0 + a1) + (a2 + a3);
}

// ================= whole problem, one cooperative launch =================
__global__ __launch_bounds__(256)
void htg_coop(const float* __restrict__ z0r, const float* __restrict__ z0i,
              const float* __restrict__ ts,  const float* __restrict__ kco,
              const float* __restrict__ rco, const float* __restrict__ alp,
              const float* __restrict__ bet, const float* __restrict__ KB,
              const float* __restrict__ RB,  float* __restrict__ outF,
              int interleaved, int out_size)
{
    cg::grid_group grid = cg::this_grid();
    __shared__ float s_W[MAT];        // 64 KB: (M^16)^T for the window stage
    __shared__ float s_v[2 * DIM];    // current vector pair
    const int blk = blockIdx.x, t = threadIdx.x;
    const int b = blk >> 3, r0 = (blk & 7) * 16;

    // ---- S1: Rsum/Ksum (16-row slab per block, 8 floats/thread) ----
    {
        float rc[NBASES], kc[NBASES];
        #pragma unroll
        for (int n = 0; n < NBASES; ++n) {
            rc[n] = rco[b * NBASES + n];
            kc[n] = kco[b * NBASES + n];
        }
        const int row = r0 + (t >> 4), j0 = (t & 15) * 8;
        #pragma unroll
        for (int jj = 0; jj < 8; ++jj) {
            const int j = j0 + jj;
            float rs = 0.f, ks = 0.f;
            #pragma unroll
            for (int n = 0; n < NBASES; ++n) {
                rs += rc[n] * RB[n * MAT + row * DIM + j];
                ks += kc[n] * KB[n * MAT + row * DIM + j];
            }
            g_rs[b * MAT + row * DIM + j] = rs;
            g_ks[b * MAT + row * DIM + j] = ks;
        }
    }
    grid.sync();

    // ---- S2: X = (alpha*skew(Ksum) - beta*(Rsum^T@Rsum))*dt + 1e-6*I ----
    {
        const float alpha = alp[b], beta = bet[b];
        const double dt = (double)ts[0];
        const int tr = t >> 6, tc = t & 63;
        const int rbase = r0 + tr * 4;
        const float* Rb = g_rs + b * MAT;
        const float* Kb = g_ks + b * MAT;
        float gx[4] = {0.f, 0.f, 0.f, 0.f}, gy[4] = {0.f, 0.f, 0.f, 0.f};
        for (int k = 0; k < DIM; ++k) {
            const float2 bv = *reinterpret_cast<const float2*>(Rb + k * DIM + tc * 2);
            #pragma unroll
            for (int i = 0; i < 4; ++i) {
                const float a = Rb[k * DIM + rbase + i];   // Rsum^T operand, broadcast
                gx[i] += a * bv.x;
                gy[i] += a * bv.y;
            }
        }
        #pragma unroll
        for (int i = 0; i < 4; ++i) {
            const int r = rbase + i;
            const int jx = tc * 2, jy = jx + 1;
            const float ksx = Kb[r * DIM + jx] - Kb[jx * DIM + r];
            const float ksy = Kb[r * DIM + jy] - Kb[jy * DIM + r];
            const float axv = alpha * ksx - beta * gx[i];   // beta * neg_gram
            const float ayv = alpha * ksy - beta * gy[i];
            double xv = (double)axv * dt; if (r == jx) xv += 1e-6;
            double yv = (double)ayv * dt; if (r == jy) yv += 1e-6;
            g_X[b * MAT + r * DIM + jx] = (float)xv;
            g_X[b * MAT + r * DIM + jy] = (float)yv;
        }
    }
    grid.sync();

    // ---- S3: X2 = X@X ----
    mm_panel<false, false, false>(g_X + b * MAT, g_X + b * MAT, g_X2 + b * MAT,
                                  nullptr, nullptr, 0, 0, 0, 0, 0, r0, t);
    grid.sync();

    // ---- S4: c0 = exp(X)^T, degree-4 Taylor, one Horner matmul:
    //          exp(X) = I + X + (I/2 + X/6 + X2/24)@X2 ----
    mm_panel<true, true, true>(nullptr, g_X2 + b * MAT, g_c0 + b * MAT,
                               g_X + b * MAT, g_X2 + b * MAT,
                               0.5f, 1.f / 6.f, 1.f / 24.f, 1.f, 1.f, r0, t);
    grid.sync();

    // ---- S5..S8: squarings (transposed chain closed under squaring) ----
    mm_panel<false, false, false>(g_c0 + b * MAT, g_c0 + b * MAT, g_c1 + b * MAT,
                                  nullptr, nullptr, 0, 0, 0, 0, 0, r0, t);
    grid.sync();
    mm_panel<false, false, false>(g_c1 + b * MAT, g_c1 + b * MAT, g_c2 + b * MAT,
                                  nullptr, nullptr, 0, 0, 0, 0, 0, r0, t);
    grid.sync();
    mm_panel<false, false, false>(g_c2 + b * MAT, g_c2 + b * MAT, g_c3 + b * MAT,
                                  nullptr, nullptr, 0, 0, 0, 0, 0, r0, t);
    grid.sync();
    mm_panel<false, false, false>(g_c3 + b * MAT, g_c3 + b * MAT, g_c4 + b * MAT,
                                  nullptr, nullptr, 0, 0, 0, 0, 0, r0, t);
    grid.sync();

    const int c = t >> 7, o = t & 127;
    const float* chain[5] = {g_c0 + b * MAT, g_c1 + b * MAT, g_c2 + b * MAT,
                             g_c3 + b * MAT, g_c4 + b * MAT};

    // ---- S9: seeds u_r = M^r z, r = 1..16, via binary bits over c0..c4.
    //      2 pair-jobs per block (512 total). W from L2. ----
    #pragma unroll
    for (int jj = 0; jj < 2; ++jj) {
        const int r = (blk & 7) * 2 + 1 + jj;
        s_v[t] = (t < DIM) ? z0r[b * DIM + t] : z0i[b * DIM + (t - DIM)];
        __syncthreads();
        #pragma unroll
        for (int k = 0; k <= 4; ++k) {
            if (r & (1 << k)) {                        // block-uniform branch
                const float acc = matvec_T(chain[k], s_v, c, o);
                __syncthreads();
                s_v[c * DIM + o] = acc;
                __syncthreads();
            }
        }
        const float val = s_v[c * DIM + o];
        g_U[((b * 2 + c) * 16 + (r - 1)) * DIM + o] = val;
        write_out(outF, b, r - 1, o, c, val, interleaved, out_size);
        __syncthreads();
    }
    grid.sync();

    // ---- S10: windows. Stage (M^16)^T in LDS; for each of the block's 2 r's,
    //      iterate u_{16q+r} = M^16 u_{16(q-1)+r}, q = 1..7. ----
    {
        const float* W16 = chain[4];
        for (int e = t * 4; e < MAT; e += 256 * 4)
            *reinterpret_cast<float4*>(s_W + e) =
                *reinterpret_cast<const float4*>(W16 + e);
        __syncthreads();
        #pragma unroll
        for (int jj = 0; jj < 2; ++jj) {
            const int r = (blk & 7) * 2 + 1 + jj;
            s_v[c * DIM + o] = g_U[((b * 2 + c) * 16 + (r - 1)) * DIM + o];
            __syncthreads();
            for (int q = 1; q <= 7; ++q) {
                const float acc = matvec_T(s_W, s_v, c, o);
                __syncthreads();
                s_v[c * DIM + o] = acc;
                write_out(outF, b, 16 * q + r - 1, o, c, acc, interleaved, out_size);
                __syncthreads();
            }
        }
    }
}

// ================= host =================
extern "C" void kernel_launch(void* const* d_in, const int* in_sizes, int n_in,
                              void* d_out, int out_size, void* d_ws, size_t ws_size,
                              hipStream_t stream)
{
    (void)in_sizes; (void)n_in; (void)d_ws; (void)ws_size;
    const float* z0r = (const float*)d_in[0];
    const float* z0i = (const float*)d_in[1];
    const float* ts  = (const float*)d_in[2];
    const float* kco = (const float*)d_in[3];
    const float* rco = (const float*)d_in[4];
    const float* alp = (const float*)d_in[5];
    const float* bet = (const float*)d_in[6];
    const float* KB  = (const float*)d_in[7];
    const float* RB  = (const float*)d_in[8];
    float* outF = (float*)d_out;

    int interleaved = (out_size >= 2 * BATCH * SSTEPS * DIM) ? 1 : 0;

    void* args[] = { &z0r, &z0i, &ts, &kco, &rco, &alp, &bet, &KB, &RB, &outF,
                     &interleaved, &out_size };
    hipLaunchCooperativeKernel((void*)htg_coop, dim3(256), dim3(256), args, 0, stream);
}

// Round 8
// 282.851 us; speedup vs baseline: 1.7960x; 1.7960x over previous
//
#include <hip/hip_runtime.h>

#define BATCH   32
#define DIM     128
#define NBASES  8
#define SSTEPS  128
#define MAT     (DIM*DIM)

// ---------- 8x8 register-tile matmul core, operands in LDS ----------
// C[i][j] += sum_k At[k][r0+i] * Bn[k][c0+j]
// At = "A transposed" layout (A[r][k] stored at At[k*128+r]) -> contiguous b128
// Bn = normal layout -> contiguous b128. All reads vectorized, no strided LDS.
__device__ __forceinline__ void mm_core(const float* __restrict__ At,
                                        const float* __restrict__ Bn,
                                        float C[8][8], int r0, int c0)
{
    #pragma unroll 2
    for (int k = 0; k < DIM; ++k) {
        const float4 a0 = *reinterpret_cast<const float4*>(At + k * DIM + r0);
        const float4 a1 = *reinterpret_cast<const float4*>(At + k * DIM + r0 + 4);
        const float4 b0 = *reinterpret_cast<const float4*>(Bn + k * DIM + c0);
        const float4 b1 = *reinterpret_cast<const float4*>(Bn + k * DIM + c0 + 4);
        const float a[8]  = {a0.x, a0.y, a0.z, a0.w, a1.x, a1.y, a1.z, a1.w};
        const float bb[8] = {b0.x, b0.y, b0.z, b0.w, b1.x, b1.y, b1.z, b1.w};
        #pragma unroll
        for (int i = 0; i < 8; ++i)
            #pragma unroll
            for (int j = 0; j < 8; ++j)
                C[i][j] += a[i] * bb[j];
    }
}

__device__ __forceinline__ void store_normal(float* __restrict__ Bn,
                                             const float C[8][8], int r0, int c0)
{
    #pragma unroll
    for (int i = 0; i < 8; ++i) {
        *reinterpret_cast<float4*>(Bn + (r0 + i) * DIM + c0) =
            make_float4(C[i][0], C[i][1], C[i][2], C[i][3]);
        *reinterpret_cast<float4*>(Bn + (r0 + i) * DIM + c0 + 4) =
            make_float4(C[i][4], C[i][5], C[i][6], C[i][7]);
    }
}

__device__ __forceinline__ void store_trans(float* __restrict__ At,
                                            const float C[8][8], int r0, int c0)
{
    #pragma unroll
    for (int j = 0; j < 8; ++j) {
        *reinterpret_cast<float4*>(At + (c0 + j) * DIM + r0) =
            make_float4(C[0][j], C[1][j], C[2][j], C[3][j]);
        *reinterpret_cast<float4*>(At + (c0 + j) * DIM + r0 + 4) =
            make_float4(C[4][j], C[5][j], C[6][j], C[7][j]);
    }
}

__device__ __forceinline__ void write_out(float* __restrict__ outF, int b, int sidx,
                                          int o, int c, float val,
                                          int interleaved, int out_size)
{
    if (interleaved) {
        const int oi = ((b * SSTEPS + sidx) * DIM + o) * 2 + c;
        if (oi < out_size) outF[oi] = val;
    } else if (c == 0) {
        const int oi = (b * SSTEPS + sidx) * DIM + o;
        if (oi < out_size) outF[oi] = val;
    }
}

// seed round: with WT = (M^(2^k))^T in LDS, u_{j+2^k} = M^(2^k) u_j for j=1..2^k.
// hist[i*32 + c*16 + slot] = u_{slot+1}[i] (component c). Dest slots disjoint
// from source slots -> no mid-round sync needed.
template<int J>
__device__ __forceinline__ void seed_round(const float* __restrict__ WT,
                                           float* __restrict__ hist,
                                           float* __restrict__ outF,
                                           int b, int s0, int t,
                                           int interleaved, int out_size)
{
    const int c = t >> 7, o = t & 127;
    float acc[J];
    #pragma unroll
    for (int s = 0; s < J; ++s) acc[s] = 0.f;
    #pragma unroll 4
    for (int i = 0; i < DIM; ++i) {
        const float w = WT[i * DIM + o];              // coalesced over lanes
        #pragma unroll
        for (int s = 0; s < J; ++s)
            acc[s] += w * hist[i * 32 + c * 16 + s0 + s];   // broadcast
    }
    #pragma unroll
    for (int s = 0; s < J; ++s) {
        const int slot = s0 + J + s;
        hist[o * 32 + c * 16 + slot] = acc[s];
        write_out(outF, b, slot, o, c, acc[s], interleaved, out_size);
    }
}

// ============ whole problem: 1 block = 1 batch, everything in LDS ============
__global__ __launch_bounds__(256, 1)
void htg_lds(const float* __restrict__ z0r, const float* __restrict__ z0i,
             const float* __restrict__ ts,  const float* __restrict__ kco,
             const float* __restrict__ rco, const float* __restrict__ alp,
             const float* __restrict__ bet, const float* __restrict__ KB,
             const float* __restrict__ RB,  float* __restrict__ outF,
             int interleaved, int out_size)
{
    __shared__ float bufA[MAT];        // 64 KB  (normal-layout operand)
    __shared__ float bufB[MAT];        // 64 KB  (transposed-layout operand)
    __shared__ float hist[DIM * 32];   // 16 KB  u-history: hist[i*32 + c*16 + slot]
    __shared__ float s_z[2 * DIM];     // 1 KB

    const int b = blockIdx.x, t = threadIdx.x;
    const int r0 = (t >> 4) * 8;       // 16 row-groups x 8 rows
    const int c0 = (t & 15) * 8;       // 16 col-groups x 8 cols

    // ---- S1: Rsum -> bufA, Ksum -> bufB (inputs are ~1 MB, shared across all
    //          blocks -> L2/L3 resident after first touch), z -> s_z ----
    {
        float rc[NBASES], kc[NBASES];
        #pragma unroll
        for (int n = 0; n < NBASES; ++n) {
            rc[n] = rco[b * NBASES + n];
            kc[n] = kco[b * NBASES + n];
        }
        #pragma unroll
        for (int q = 0; q < 16; ++q) {
            const int e = (q * 256 + t) * 4;
            float4 r4 = {0.f, 0.f, 0.f, 0.f}, k4 = {0.f, 0.f, 0.f, 0.f};
            #pragma unroll
            for (int n = 0; n < NBASES; ++n) {
                const float4 rv = *reinterpret_cast<const float4*>(RB + n * MAT + e);
                const float4 kv = *reinterpret_cast<const float4*>(KB + n * MAT + e);
                r4.x += rc[n] * rv.x; r4.y += rc[n] * rv.y;
                r4.z += rc[n] * rv.z; r4.w += rc[n] * rv.w;
                k4.x += kc[n] * kv.x; k4.y += kc[n] * kv.y;
                k4.z += kc[n] * kv.z; k4.w += kc[n] * kv.w;
            }
            *reinterpret_cast<float4*>(bufA + e) = r4;
            *reinterpret_cast<float4*>(bufB + e) = k4;
        }
        s_z[t] = (t < DIM) ? z0r[b * DIM + t] : z0i[b * DIM + (t - DIM)];
    }
    __syncthreads();

    float C[8][8];

    // ---- P1: gram = Rsum^T @ Rsum (both operand parts are rows of bufA),
    //          epilogue -> X = (alpha*skew(Ksum) - beta*gram)*dt + 1e-6*I ----
    #pragma unroll
    for (int i = 0; i < 8; ++i)
        #pragma unroll
        for (int j = 0; j < 8; ++j) C[i][j] = 0.f;
    mm_core(bufA, bufA, C, r0, c0);
    {
        const float alpha = alp[b], beta = bet[b];
        const double dt = (double)ts[0];
        #pragma unroll
        for (int i = 0; i < 8; ++i)
            #pragma unroll
            for (int j = 0; j < 8; ++j) {
                const int r = r0 + i, cc = c0 + j;
                const float ks  = bufB[r * DIM + cc];
                const float kst = bufB[cc * DIM + r];
                double xv = (double)(alpha * (ks - kst) - beta * C[i][j]) * dt;
                if (r == cc) xv += 1e-6;
                C[i][j] = (float)xv;
            }
    }
    __syncthreads();
    store_normal(bufA, C, r0, c0);   // bufA = X
    store_trans (bufB, C, r0, c0);   // bufB = X^T (A-operand for mm1..mm3)
    __syncthreads();

    // ---- exp(X), degree 4: M = I + X@(I + X@(I/2 + X@(I/6·?))) rewritten as
    //  Q = I/2 + X/6 + X^2/24 ; P = I + X@Q ; M = I + X@P ----
    // mm1: acc = X@X ; Q = acc/24 + X/6 + I/2
    #pragma unroll
    for (int i = 0; i < 8; ++i)
        #pragma unroll
        for (int j = 0; j < 8; ++j) C[i][j] = 0.f;
    mm_core(bufB, bufA, C, r0, c0);
    #pragma unroll
    for (int i = 0; i < 8; ++i)
        #pragma unroll
        for (int j = 0; j < 8; ++j) {
            const int r = r0 + i, cc = c0 + j;
            float v = C[i][j] * (1.f / 24.f) + bufA[r * DIM + cc] * (1.f / 6.f);
            if (r == cc) v += 0.5f;
            C[i][j] = v;
        }
    __syncthreads();
    store_normal(bufA, C, r0, c0);   // bufA = Q   (bufB keeps X^T)
    __syncthreads();

    // mm2: P = I + X@Q
    #pragma unroll
    for (int i = 0; i < 8; ++i)
        #pragma unroll
        for (int j = 0; j < 8; ++j) C[i][j] = 0.f;
    mm_core(bufB, bufA, C, r0, c0);
    #pragma unroll
    for (int i = 0; i < 8; ++i) C[i][i + 0] += (r0 + i == c0 + i) ? 0.f : 0.f;  // no-op
    #pragma unroll
    for (int i = 0; i < 8; ++i)
        #pragma unroll
        for (int j = 0; j < 8; ++j)
            if (r0 + i == c0 + j) C[i][j] += 1.f;
    __syncthreads();
    store_normal(bufA, C, r0, c0);   // bufA = P
    __syncthreads();

    // mm3: M = I + X@P
    #pragma unroll
    for (int i = 0; i < 8; ++i)
        #pragma unroll
        for (int j = 0; j < 8; ++j) C[i][j] = 0.f;
    mm_core(bufB, bufA, C, r0, c0);
    #pragma unroll
    for (int i = 0; i < 8; ++i)
        #pragma unroll
        for (int j = 0; j < 8; ++j)
            if (r0 + i == c0 + j) C[i][j] += 1.f;
    __syncthreads();
    store_normal(bufA, C, r0, c0);   // bufA = M
    store_trans (bufB, C, r0, c0);   // bufB = M^T
    __syncthreads();

    // ---- seeds u1 = Mz, u2 = M u1 (W = M resident) ----
    {
        const int c = t >> 7, o = t & 127;
        float acc = 0.f;
        #pragma unroll 4
        for (int i = 0; i < DIM; ++i) acc += bufB[i * DIM + o] * s_z[c * DIM + i];
        hist[o * 32 + c * 16] = acc;
        write_out(outF, b, 0, o, c, acc, interleaved, out_size);
    }
    __syncthreads();
    seed_round<1>(bufB, hist, outF, b, 0, t, interleaved, out_size);   // u2
    __syncthreads();

    // ---- squarings with interleaved seed rounds ----
    // sq1 -> M^2 ; seeds u3,u4
    #pragma unroll
    for (int i = 0; i < 8; ++i)
        #pragma unroll
        for (int j = 0; j < 8; ++j) C[i][j] = 0.f;
    mm_core(bufB, bufA, C, r0, c0);
    __syncthreads();
    store_normal(bufA, C, r0, c0); store_trans(bufB, C, r0, c0);
    __syncthreads();
    seed_round<2>(bufB, hist, outF, b, 0, t, interleaved, out_size);
    __syncthreads();

    // sq2 -> M^4 ; seeds u5..u8
    #pragma unroll
    for (int i = 0; i < 8; ++i)
        #pragma unroll
        for (int j = 0; j < 8; ++j) C[i][j] = 0.f;
    mm_core(bufB, bufA, C, r0, c0);
    __syncthreads();
    store_normal(bufA, C, r0, c0); store_trans(bufB, C, r0, c0);
    __syncthreads();
    seed_round<4>(bufB, hist, outF, b, 0, t, interleaved, out_size);
    __syncthreads();

    // sq3 -> M^8 ; seeds u9..u16
    #pragma unroll
    for (int i = 0; i < 8; ++i)
        #pragma unroll
        for (int j = 0; j < 8; ++j) C[i][j] = 0.f;
    mm_core(bufB, bufA, C, r0, c0);
    __syncthreads();
    store_normal(bufA, C, r0, c0); store_trans(bufB, C, r0, c0);
    __syncthreads();
    seed_round<8>(bufB, hist, outF, b, 0, t, interleaved, out_size);
    __syncthreads();

    // sq4 -> M^16
    #pragma unroll
    for (int i = 0; i < 8; ++i)
        #pragma unroll
        for (int j = 0; j < 8; ++j) C[i][j] = 0.f;
    mm_core(bufB, bufA, C, r0, c0);
    __syncthreads();
    store_trans(bufB, C, r0, c0);    // only (M^16)^T needed from here on
    __syncthreads();

    // ---- 7 windows: U <- M^16 @ U  (U = hist, 128 x 32), 4x4 tiles ----
    {
        const int og4 = (t >> 3) * 4;    // 32 o-groups x 4 rows
        const int vg4 = (t & 7) * 4;     // 8 v-groups x 4 vectors
        for (int q = 1; q <= 7; ++q) {
            float acc[4][4];
            #pragma unroll
            for (int i = 0; i < 4; ++i)
                #pragma unroll
                for (int j = 0; j < 4; ++j) acc[i][j] = 0.f;
            #pragma unroll 2
            for (int i = 0; i < DIM; ++i) {
                const float4 a  = *reinterpret_cast<const float4*>(bufB + i * DIM + og4);
                const float4 bb = *reinterpret_cast<const float4*>(hist + i * 32 + vg4);
                const float av[4] = {a.x, a.y, a.z, a.w};
                const float bv[4] = {bb.x, bb.y, bb.z, bb.w};
                #pragma unroll
                for (int ii = 0; ii < 4; ++ii)
                    #pragma unroll
                    for (int vv = 0; vv < 4; ++vv)
                        acc[ii][vv] += av[ii] * bv[vv];
            }
            __syncthreads();   // all reads of hist complete before overwrite
            #pragma unroll
            for (int ii = 0; ii < 4; ++ii)
                *reinterpret_cast<float4*>(hist + (og4 + ii) * 32 + vg4) =
                    make_float4(acc[ii][0], acc[ii][1], acc[ii][2], acc[ii][3]);
            #pragma unroll
            for (int vv = 0; vv < 4; ++vv) {
                const int v = vg4 + vv, c = v >> 4, slot = v & 15;
                const int sidx = 16 * q + slot;
                #pragma unroll
                for (int ii = 0; ii < 4; ++ii)
                    write_out(outF, b, sidx, og4 + ii, c, acc[ii][vv],
                              interleaved, out_size);
            }
            __syncthreads();
        }
    }
}

// ================= host =================
extern "C" void kernel_launch(void* const* d_in, const int* in_sizes, int n_in,
                              void* d_out, int out_size, void* d_ws, size_t ws_size,
                              hipStream_t stream)
{
    (void)in_sizes; (void)n_in; (void)d_ws; (void)ws_size;
    const float* z0r = (const float*)d_in[0];
    const float* z0i = (const float*)d_in[1];
    const float* ts  = (const float*)d_in[2];
    const float* kco = (const float*)d_in[3];
    const float* rco = (const float*)d_in[4];
    const float* alp = (const float*)d_in[5];
    const float* bet = (const float*)d_in[6];
    const float* KB  = (const float*)d_in[7];
    const float* RB  = (const float*)d_in[8];
    float* outF = (float*)d_out;

    const int interleaved = (out_size >= 2 * BATCH * SSTEPS * DIM) ? 1 : 0;

    htg_lds<<<dim3(BATCH), dim3(256), 0, stream>>>(
        z0r, z0i, ts, kco, rco, alp, bet, KB, RB, outF, interleaved, out_size);
}

// Round 9
// 128.012 us; speedup vs baseline: 3.9684x; 2.2096x over previous
//
#include <hip/hip_runtime.h>

#define BATCH   32
#define DIM     128
#define NBASES  8
#define SSTEPS  128
#define LDA     136   // padded row (shorts): 272 B stride -> 4-bank shift/row

typedef __attribute__((ext_vector_type(8))) short s8v;   // 8 bf16 (4 VGPR)
typedef __attribute__((ext_vector_type(4))) float f4v;   // MFMA acc

__device__ __forceinline__ f4v mf(s8v a, s8v b, f4v c) {
    return __builtin_amdgcn_mfma_f32_16x16x32_bf16(a, b, c, 0, 0, 0);
}
__device__ __forceinline__ s8v ld8(const short* p) {
    return *reinterpret_cast<const s8v*>(p);
}
__device__ __forceinline__ float upbf(short h) {
    return __uint_as_float(((unsigned)(unsigned short)h) << 16);
}
// split fp32 -> bf16 hi + bf16 lo (truncation; dropped residual ~2^-16 rel)
__device__ __forceinline__ void splitbf(float v, short& hi, short& lo) {
    const unsigned u = __float_as_uint(v);
    hi = (short)(u >> 16);
    const float fh = __uint_as_float(u & 0xffff0000u);
    lo = (short)(__float_as_uint(v - fh) >> 16);
}

__device__ __forceinline__ void write_out(float* __restrict__ outF, int b, int sidx,
                                          int o, int c, float val,
                                          int interleaved, int out_size)
{
    if (interleaved) {
        const int oi = ((b * SSTEPS + sidx) * DIM + o) * 2 + c;
        if (oi < out_size) outF[oi] = val;
    } else if (c == 0) {
        const int oi = (b * SSTEPS + sidx) * DIM + o;
        if (oi < out_size) outF[oi] = val;
    }
}

// ---- full 128x128x128 split-bf16 MFMA matmul: 8 waves, wave = 32x64 tile ----
// A from "norm" planes (A[m][k] at m*LDA+k), B from "trans" planes
// (holding B^T: buf[n*LDA+k] = B[k][n]). acc[mi][ni] are 16x16 C tiles.
__device__ __forceinline__ void mm_full(const short* __restrict__ Ah,
                                        const short* __restrict__ Al,
                                        const short* __restrict__ Bh,
                                        const short* __restrict__ Bl,
                                        f4v acc[2][4], int w, int lane)
{
    const int l15 = lane & 15, quad = lane >> 4;
    const int mb = (w & 3) * 32, nb = (w >> 2) * 64;
    #pragma unroll
    for (int kk = 0; kk < DIM; kk += 32) {
        const int ko = kk + quad * 8;
        const s8v a0h = ld8(Ah + (mb +      l15) * LDA + ko);
        const s8v a0l = ld8(Al + (mb +      l15) * LDA + ko);
        const s8v a1h = ld8(Ah + (mb + 16 + l15) * LDA + ko);
        const s8v a1l = ld8(Al + (mb + 16 + l15) * LDA + ko);
        #pragma unroll
        for (int ni = 0; ni < 4; ++ni) {
            const s8v bh = ld8(Bh + (nb + ni * 16 + l15) * LDA + ko);
            const s8v bl = ld8(Bl + (nb + ni * 16 + l15) * LDA + ko);
            acc[0][ni] = mf(a0h, bh, acc[0][ni]);
            acc[0][ni] = mf(a0h, bl, acc[0][ni]);
            acc[0][ni] = mf(a0l, bh, acc[0][ni]);
            acc[1][ni] = mf(a1h, bh, acc[1][ni]);
            acc[1][ni] = mf(a1h, bl, acc[1][ni]);
            acc[1][ni] = mf(a1l, bh, acc[1][ni]);
        }
    }
}

// ---- 128x32x128 MFMA (seed rounds & windows): wave = one 16-row strip,
// B from histT planes (ht[v*LDA+i] = u_v[i]); acc[ci] = C tile cols c*16.. ----
__device__ __forceinline__ void mm_rw(const short* __restrict__ Ah,
                                      const short* __restrict__ Al,
                                      const short* __restrict__ Hh,
                                      const short* __restrict__ Hl,
                                      f4v acc[2], int w, int lane)
{
    const int l15 = lane & 15, quad = lane >> 4;
    const int mb = w * 16;
    #pragma unroll
    for (int kk = 0; kk < DIM; kk += 32) {
        const int ko = kk + quad * 8;
        const s8v ah = ld8(Ah + (mb + l15) * LDA + ko);
        const s8v al = ld8(Al + (mb + l15) * LDA + ko);
        #pragma unroll
        for (int ci = 0; ci < 2; ++ci) {
            const s8v bh = ld8(Hh + (ci * 16 + l15) * LDA + ko);
            const s8v bl = ld8(Hl + (ci * 16 + l15) * LDA + ko);
            acc[ci] = mf(ah, bh, acc[ci]);
            acc[ci] = mf(ah, bl, acc[ci]);
            acc[ci] = mf(al, bh, acc[ci]);
        }
    }
}

// ============ whole problem: 1 block = 1 batch, MFMA chain in LDS ============
__global__ __launch_bounds__(512, 1)
void htg_mfma(const float* __restrict__ z0r, const float* __restrict__ z0i,
              const float* __restrict__ ts,  const float* __restrict__ kco,
              const float* __restrict__ rco, const float* __restrict__ alp,
              const float* __restrict__ bet, const float* __restrict__ KB,
              const float* __restrict__ RB,  float* __restrict__ outF,
              int interleaved, int out_size)
{
    __shared__ short nm_hi[DIM * LDA], nm_lo[DIM * LDA];   // row-major planes
    __shared__ short tr_hi[DIM * LDA], tr_lo[DIM * LDA];   // transposed planes
    __shared__ short ht_hi[32 * LDA],  ht_lo[32 * LDA];    // u-table (v rows)
    __shared__ float s_z[2 * DIM];

    const int b = blockIdx.x, t = threadIdx.x;
    const int w = t >> 6, lane = t & 63;
    const int l15 = lane & 15, quad = lane >> 4;
    const f4v z4 = {0.f, 0.f, 0.f, 0.f};

    // ---- S1: Rsum -> trans planes (tr[c*LDA+r] = R[r][c]); Ksum -> norm planes ----
    {
        float rc[NBASES], kc[NBASES];
        #pragma unroll
        for (int n = 0; n < NBASES; ++n) {
            rc[n] = rco[b * NBASES + n];
            kc[n] = kco[b * NBASES + n];
        }
        #pragma unroll
        for (int q = 0; q < 8; ++q) {
            const int e = q * 2048 + t * 4;
            float4 r4 = {0.f, 0.f, 0.f, 0.f}, k4 = {0.f, 0.f, 0.f, 0.f};
            #pragma unroll
            for (int n = 0; n < NBASES; ++n) {
                const float4 rv = *reinterpret_cast<const float4*>(RB + n * DIM * DIM + e);
                const float4 kv = *reinterpret_cast<const float4*>(KB + n * DIM * DIM + e);
                r4.x += rc[n] * rv.x; r4.y += rc[n] * rv.y;
                r4.z += rc[n] * rv.z; r4.w += rc[n] * rv.w;
                k4.x += kc[n] * kv.x; k4.y += kc[n] * kv.y;
                k4.z += kc[n] * kv.z; k4.w += kc[n] * kv.w;
            }
            const int r = e >> 7, c = e & 127;
            const float rr[4] = {r4.x, r4.y, r4.z, r4.w};
            const float kk[4] = {k4.x, k4.y, k4.z, k4.w};
            #pragma unroll
            for (int j = 0; j < 4; ++j) {
                short hi, lo;
                splitbf(rr[j], hi, lo);
                tr_hi[(c + j) * LDA + r] = hi; tr_lo[(c + j) * LDA + r] = lo;
                splitbf(kk[j], hi, lo);
                nm_hi[r * LDA + c + j] = hi;  nm_lo[r * LDA + c + j] = lo;
            }
        }
        if (t < 2 * DIM)
            s_z[t] = (t < DIM) ? z0r[b * DIM + t] : z0i[b * DIM + (t - DIM)];
    }
    __syncthreads();

    f4v acc[2][4];
    const int mb = (w & 3) * 32, nb = (w >> 2) * 64;

    // ---- Op1: gram = R^T@R (A & B frags both from trans(R));
    //      epilogue -> X = (alpha*(K - K^T) - beta*gram)*dt + 1e-6*I ----
    #pragma unroll
    for (int i = 0; i < 2; ++i)
        #pragma unroll
        for (int j = 0; j < 4; ++j) acc[i][j] = z4;
    mm_full(tr_hi, tr_lo, tr_hi, tr_lo, acc, w, lane);
    __syncthreads();
    {
        const float alpha = alp[b], beta = bet[b], dtf = ts[0];
        #pragma unroll
        for (int mi = 0; mi < 2; ++mi)
            #pragma unroll
            for (int ni = 0; ni < 4; ++ni)
                #pragma unroll
                for (int r = 0; r < 4; ++r) {
                    const int row = mb + mi * 16 + quad * 4 + r;
                    const int col = nb + ni * 16 + l15;
                    const float k1 = upbf(nm_hi[row * LDA + col]) + upbf(nm_lo[row * LDA + col]);
                    const float k2 = upbf(nm_hi[col * LDA + row]) + upbf(nm_lo[col * LDA + row]);
                    float x = (alpha * (k1 - k2) - beta * acc[mi][ni][r]) * dtf;
                    if (row == col) x += 1e-6f;
                    acc[mi][ni][r] = x;
                }
    }
    __syncthreads();   // all K reads done before overwriting norm
    #pragma unroll
    for (int mi = 0; mi < 2; ++mi)
        #pragma unroll
        for (int ni = 0; ni < 4; ++ni)
            #pragma unroll
            for (int r = 0; r < 4; ++r) {
                const int row = mb + mi * 16 + quad * 4 + r;
                const int col = nb + ni * 16 + l15;
                short hi, lo;
                splitbf(acc[mi][ni][r], hi, lo);
                nm_hi[row * LDA + col] = hi; nm_lo[row * LDA + col] = lo;  // X
                tr_hi[col * LDA + row] = hi; tr_lo[col * LDA + row] = lo;  // X^T
            }
    __syncthreads();

    // ---- Op2: C = X@X ; Q = C/24 + X/6 + I/2 -> trans only (norm keeps X) ----
    #pragma unroll
    for (int i = 0; i < 2; ++i)
        #pragma unroll
        for (int j = 0; j < 4; ++j) acc[i][j] = z4;
    mm_full(nm_hi, nm_lo, tr_hi, tr_lo, acc, w, lane);
    __syncthreads();
    #pragma unroll
    for (int mi = 0; mi < 2; ++mi)
        #pragma unroll
        for (int ni = 0; ni < 4; ++ni)
            #pragma unroll
            for (int r = 0; r < 4; ++r) {
                const int row = mb + mi * 16 + quad * 4 + r;
                const int col = nb + ni * 16 + l15;
                const float xv = upbf(nm_hi[row * LDA + col]) + upbf(nm_lo[row * LDA + col]);
                float v = acc[mi][ni][r] * (1.f / 24.f) + xv * (1.f / 6.f);
                if (row == col) v += 0.5f;
                short hi, lo;
                splitbf(v, hi, lo);
                tr_hi[col * LDA + row] = hi; tr_lo[col * LDA + row] = lo;  // Q^T
            }
    __syncthreads();

    // ---- Op3: P = I + X@Q -> trans only ----
    #pragma unroll
    for (int i = 0; i < 2; ++i)
        #pragma unroll
        for (int j = 0; j < 4; ++j) acc[i][j] = z4;
    mm_full(nm_hi, nm_lo, tr_hi, tr_lo, acc, w, lane);
    __syncthreads();
    #pragma unroll
    for (int mi = 0; mi < 2; ++mi)
        #pragma unroll
        for (int ni = 0; ni < 4; ++ni)
            #pragma unroll
            for (int r = 0; r < 4; ++r) {
                const int row = mb + mi * 16 + quad * 4 + r;
                const int col = nb + ni * 16 + l15;
                float v = acc[mi][ni][r];
                if (row == col) v += 1.f;
                short hi, lo;
                splitbf(v, hi, lo);
                tr_hi[col * LDA + row] = hi; tr_lo[col * LDA + row] = lo;  // P^T
            }
    __syncthreads();

    // ---- Op4: M = I + X@P -> BOTH (norm overwrites X) ----
    #pragma unroll
    for (int i = 0; i < 2; ++i)
        #pragma unroll
        for (int j = 0; j < 4; ++j) acc[i][j] = z4;
    mm_full(nm_hi, nm_lo, tr_hi, tr_lo, acc, w, lane);
    __syncthreads();
    #pragma unroll
    for (int mi = 0; mi < 2; ++mi)
        #pragma unroll
        for (int ni = 0; ni < 4; ++ni)
            #pragma unroll
            for (int r = 0; r < 4; ++r) {
                const int row = mb + mi * 16 + quad * 4 + r;
                const int col = nb + ni * 16 + l15;
                float v = acc[mi][ni][r];
                if (row == col) v += 1.f;
                short hi, lo;
                splitbf(v, hi, lo);
                nm_hi[row * LDA + col] = hi; nm_lo[row * LDA + col] = lo;
                tr_hi[col * LDA + row] = hi; tr_lo[col * LDA + row] = lo;
            }
    __syncthreads();

    // ---- u1 = M z (VALU, fp32 from trans planes: tr[i*LDA+o] = M[o][i]) ----
    if (t < 2 * DIM) {
        const int c = t >> 7, o = t & 127;
        float a = 0.f;
        #pragma unroll 4
        for (int i = 0; i < DIM; ++i)
            a += (upbf(tr_hi[i * LDA + o]) + upbf(tr_lo[i * LDA + o])) * s_z[c * DIM + i];
        short hi, lo;
        splitbf(a, hi, lo);
        ht_hi[(c * 16) * LDA + o] = hi;
        ht_lo[(c * 16) * LDA + o] = lo;
        write_out(outF, b, 0, o, c, a, interleaved, out_size);
    }
    __syncthreads();

    // ---- seed rounds (J = 2^k, W = M^J in norm) interleaved with squarings ----
    #pragma unroll
    for (int stage = 0; stage < 4; ++stage) {
        const int J = 1 << stage;
        // round: slots [J..2J-1] = W @ slots [0..J-1]
        f4v a2[2] = {z4, z4};
        mm_rw(nm_hi, nm_lo, ht_hi, ht_lo, a2, w, lane);
        __syncthreads();
        if (l15 < J) {
            #pragma unroll
            for (int ci = 0; ci < 2; ++ci)
                #pragma unroll
                for (int r = 0; r < 4; ++r) {
                    const int o = w * 16 + quad * 4 + r;
                    const float v = a2[ci][r];
                    short hi, lo;
                    splitbf(v, hi, lo);
                    ht_hi[(ci * 16 + l15 + J) * LDA + o] = hi;
                    ht_lo[(ci * 16 + l15 + J) * LDA + o] = lo;
                    write_out(outF, b, l15 + J, o, ci, v, interleaved, out_size);
                }
        }
        __syncthreads();
        // squaring: M^(2J) = (M^J)^2 -> norm + trans
        #pragma unroll
        for (int i = 0; i < 2; ++i)
            #pragma unroll
            for (int j = 0; j < 4; ++j) acc[i][j] = z4;
        mm_full(nm_hi, nm_lo, tr_hi, tr_lo, acc, w, lane);
        __syncthreads();
        #pragma unroll
        for (int mi = 0; mi < 2; ++mi)
            #pragma unroll
            for (int ni = 0; ni < 4; ++ni)
                #pragma unroll
                for (int r = 0; r < 4; ++r) {
                    const int row = mb + mi * 16 + quad * 4 + r;
                    const int col = nb + ni * 16 + l15;
                    short hi, lo;
                    splitbf(acc[mi][ni][r], hi, lo);
                    nm_hi[row * LDA + col] = hi; nm_lo[row * LDA + col] = lo;
                    tr_hi[col * LDA + row] = hi; tr_lo[col * LDA + row] = lo;
                }
        __syncthreads();
    }

    // ---- 7 windows: all 32 slots <- M^16 @ slots (in place), sidx = 16q+slot ----
    for (int q = 1; q <= 7; ++q) {
        f4v a2[2] = {z4, z4};
        mm_rw(nm_hi, nm_lo, ht_hi, ht_lo, a2, w, lane);
        __syncthreads();
        #pragma unroll
        for (int ci = 0; ci < 2; ++ci)
            #pragma unroll
            for (int r = 0; r < 4; ++r) {
                const int o = w * 16 + quad * 4 + r;
                const float v = a2[ci][r];
                short hi, lo;
                splitbf(v, hi, lo);
                ht_hi[(ci * 16 + l15) * LDA + o] = hi;
                ht_lo[(ci * 16 + l15) * LDA + o] = lo;
                write_out(outF, b, 16 * q + l15, o, ci, v, interleaved, out_size);
            }
        __syncthreads();
    }
}

// ================= host =================
extern "C" void kernel_launch(void* const* d_in, const int* in_sizes, int n_in,
                              void* d_out, int out_size, void* d_ws, size_t ws_size,
                              hipStream_t stream)
{
    (void)in_sizes; (void)n_in; (void)d_ws; (void)ws_size;
    const float* z0r = (const float*)d_in[0];
    const float* z0i = (const float*)d_in[1];
    const float* ts  = (const float*)d_in[2];
    const float* kco = (const float*)d_in[3];
    const float* rco = (const float*)d_in[4];
    const float* alp = (const float*)d_in[5];
    const float* bet = (const float*)d_in[6];
    const float* KB  = (const float*)d_in[7];
    const float* RB  = (const float*)d_in[8];
    float* outF = (float*)d_out;

    const int interleaved = (out_size >= 2 * BATCH * SSTEPS * DIM) ? 1 : 0;

    htg_mfma<<<dim3(BATCH), dim3(512), 0, stream>>>(
        z0r, z0i, ts, kco, rco, alp, bet, KB, RB, outF, interleaved, out_size);
}